// Round 4
// baseline (710.206 us; speedup 1.0000x reference)
//
#include <hip/hip_runtime.h>
#include <hip/hip_bf16.h>
#include <stdint.h>

#define EN    8
#define DIN   512
#define HID   1024
#define BATCH 16384
#define LN_EPS 1e-5f

typedef __bf16   bf16x8 __attribute__((ext_vector_type(8)));
typedef float    f32x4  __attribute__((ext_vector_type(4)));
typedef uint16_t u16x8  __attribute__((ext_vector_type(8)));
typedef uint16_t u16x4  __attribute__((ext_vector_type(4)));
typedef float    fl4    __attribute__((ext_vector_type(4)));

__device__ __forceinline__ uint16_t f2bf(float f) {
  uint32_t x = __builtin_bit_cast(uint32_t, f);
  uint32_t r = (x + 0x7fffu + ((x >> 16) & 1u)) >> 16;  // RNE
  return (uint16_t)r;
}
__device__ __forceinline__ float bf2f(uint16_t u) {
  return __builtin_bit_cast(float, (uint32_t)u << 16);
}

__device__ __forceinline__ void gload16(const uint16_t* g, uint16_t* lds) {
  __builtin_amdgcn_global_load_lds(
      (const __attribute__((address_space(1))) uint32_t*)g,
      (__attribute__((address_space(3))) uint32_t*)lds, 16, 0, 0);
}

__device__ __forceinline__ f32x4 MF(bf16x8 a, bf16x8 b, f32x4 c) {
  return __builtin_amdgcn_mfma_f32_16x16x32_bf16(a, b, c, 0, 0, 0);
}

// ---------------- conversion: fp32 -> bf16 ----------------
__global__ __launch_bounds__(256) void cvt_bf16(const float* __restrict__ src,
                                                uint16_t* __restrict__ dst, long n) {
  long i = ((long)blockIdx.x * 256 + threadIdx.x) * 4;
  if (i >= n) return;
  fl4 v = *(const fl4*)(src + i);
  u16x4 o;
  #pragma unroll
  for (int j = 0; j < 4; ++j) o[j] = f2bf(v[j]);
  *(u16x4*)(dst + i) = o;
}

// ---------------- transpose + convert: [E][R][C] fp32 -> [E][C][R] bf16 ----------------
__global__ __launch_bounds__(256) void transpose_cvt(const float* __restrict__ src,
                                                     uint16_t* __restrict__ dst,
                                                     int R, int C) {
  __shared__ float tile[32][33];
  const int e = blockIdx.z;
  const int c0 = blockIdx.x * 32;
  const int r0 = blockIdx.y * 32;
  const int tx = threadIdx.x & 31, ty = threadIdx.x >> 5;
  const float* s = src + (size_t)e * R * C;
  uint16_t*    d = dst + (size_t)e * R * C;
  #pragma unroll
  for (int i = 0; i < 32; i += 8)
    tile[ty + i][tx] = s[(size_t)(r0 + ty + i) * C + (c0 + tx)];
  __syncthreads();
  #pragma unroll
  for (int i = 0; i < 32; i += 8)
    d[(size_t)(c0 + ty + i) * R + (r0 + tx)] = f2bf(tile[tx][ty + i]);
}

// ================= 256x256 8-phase GEMM (m201-style, plain HIP) =================
// C[e][M][HID] = A[e][M][K] * Bt[e][HID][K]^T + bias[e][HID]
// 512 threads = 8 waves (2M x 4N), BK=64, LDS 128 KiB (2 dbuf x (A 32K + B 32K)).
// Swizzle: logical (row,k8unit) lives at byte row*128 + ((k8 ^ (row&7))*16);
// staged via linear LDS dest + pre-swizzled GLOBAL source (rule 21).
__global__ __launch_bounds__(512, 2) void gemm256(
    const uint16_t* __restrict__ A, size_t a_estride,
    const uint16_t* __restrict__ Bt,
    const float*    __restrict__ bias,
    uint16_t*       __restrict__ C,
    int M, int K) {
  __shared__ __attribute__((aligned(16))) char lds[131072];
  const int tid = threadIdx.x;
  const int bx  = blockIdx.x;
  const int e   = bx & 7;            // member -> XCD pinning (weights L2-resident)
  const int t   = bx >> 3;
  const int mt  = t >> 2;            // nt inner: consecutive blocks share A panel
  const int nt  = t & 3;
  const int NT  = K >> 6;            // K-tiles of 64
  const int HT  = NT * 4;            // half-tiles (order per tile: B0,B1,A0,A1)

  const uint16_t* Ae = A + (size_t)e * a_estride + (size_t)(mt * 256) * K;
  const uint16_t* Be = Bt + ((size_t)e * HID + nt * 256) * K;

  const int l  = tid & 63, wid = tid >> 6;
  const int wr = wid >> 2, wc = wid & 3;
  const int fr = l & 15, kq = l >> 4, f7 = fr & 7;

  // staging: thread t covers rows (t>>3) and (t>>3)+64 of a 128-row half, k-unit (t&7)
  const int srow = tid >> 3;
  const int k8s  = (tid & 7) ^ (srow & 7);          // pre-swizzled global k-unit
  const uint16_t* pA = Ae + (size_t)srow * K + k8s * 8;
  const uint16_t* pB = Be + (size_t)srow * K + k8s * 8;
  char* ldst = lds + tid * 16;

  // ds_read bases (swizzled): row&7 == fr&7 for all frag rows (mi*16 doesn't touch low 3 bits)
  const int aoff = wr * 16384 + fr * 128 + ((kq ^ f7) << 4);
  const int boff = 32768 + (wc >> 1) * 16384 + (((wc & 1) * 64 + fr) << 7) + ((kq ^ f7) << 4);

  f32x4 acc[8][4];
  #pragma unroll
  for (int i = 0; i < 8; ++i)
    #pragma unroll
    for (int j = 0; j < 4; ++j) acc[i][j] = (f32x4)0.0f;

  auto STAGE = [&](int ht) {
    const int kt2 = ht >> 2, wh = ht & 3;
    char* db = ldst + (kt2 & 1) * 65536;
    if (wh >= 2) {                                   // A half (wh-2)
      const int h = wh - 2;
      const uint16_t* sp = pA + (size_t)(h * 128) * K + kt2 * 64;
      char* d = db + h * 16384;
      gload16(sp, (uint16_t*)d);
      gload16(sp + (size_t)64 * K, (uint16_t*)(d + 8192));
    } else {                                         // B half wh
      const uint16_t* sp = pB + (size_t)(wh * 128) * K + kt2 * 64;
      char* d = db + 32768 + wh * 16384;
      gload16(sp, (uint16_t*)d);
      gload16(sp + (size_t)64 * K, (uint16_t*)(d + 8192));
    }
  };

  // prologue: stage 7 half-tiles (kt0 fully + kt1 B0,B1,A0); wait kt0 landed
  int s = 0;
  for (; s < 7; ++s) STAGE(s);
  asm volatile("s_waitcnt vmcnt(6)" ::: "memory");   // 14 issued, <=6 out -> kt0's 8 done
  asm volatile("s_barrier" ::: "memory");

  for (int kt = 0; kt < NT; ++kt) {
    const char* rb = lds + (kt & 1) * 65536;
    bf16x8 af[4][2], bv[4][2];
    // ---- phase 0: read af(mi0-3) + all bf; MFMA Q0 (mi0-3, ni0-1) ----
    #pragma unroll
    for (int mi = 0; mi < 4; ++mi) {
      af[mi][0] = *(const bf16x8*)(rb + (aoff + mi * 2048));
      af[mi][1] = *(const bf16x8*)(rb + ((aoff + mi * 2048) ^ 64));
    }
    #pragma unroll
    for (int ni = 0; ni < 4; ++ni) {
      bv[ni][0] = *(const bf16x8*)(rb + (boff + ni * 2048));
      bv[ni][1] = *(const bf16x8*)(rb + ((boff + ni * 2048) ^ 64));
    }
    if (s < HT) STAGE(s++);
    asm volatile("s_barrier" ::: "memory");
    __builtin_amdgcn_s_setprio(1);
    #pragma unroll
    for (int mi = 0; mi < 4; ++mi)
      #pragma unroll
      for (int ni = 0; ni < 2; ++ni) {
        acc[mi][ni] = MF(af[mi][0], bv[ni][0], acc[mi][ni]);
        acc[mi][ni] = MF(af[mi][1], bv[ni][1], acc[mi][ni]);
      }
    __builtin_amdgcn_s_setprio(0);
    asm volatile("s_barrier" ::: "memory");
    // ---- phase 1: MFMA Q1 (mi0-3, ni2-3); tail: reload af <- mi4-7 ----
    if (s < HT) STAGE(s++);
    asm volatile("s_barrier" ::: "memory");
    __builtin_amdgcn_s_setprio(1);
    #pragma unroll
    for (int mi = 0; mi < 4; ++mi)
      #pragma unroll
      for (int ni = 2; ni < 4; ++ni) {
        acc[mi][ni] = MF(af[mi][0], bv[ni][0], acc[mi][ni]);
        acc[mi][ni] = MF(af[mi][1], bv[ni][1], acc[mi][ni]);
      }
    __builtin_amdgcn_s_setprio(0);
    #pragma unroll
    for (int mi = 0; mi < 4; ++mi) {
      af[mi][0] = *(const bf16x8*)(rb + (aoff + (mi + 4) * 2048));
      af[mi][1] = *(const bf16x8*)(rb + ((aoff + (mi + 4) * 2048) ^ 64));
    }
    asm volatile("s_barrier" ::: "memory");
    // ---- phase 2: MFMA Q2 (mi4-7, ni0-1) ----
    if (s < HT) STAGE(s++);
    asm volatile("s_barrier" ::: "memory");
    __builtin_amdgcn_s_setprio(1);
    #pragma unroll
    for (int mi = 0; mi < 4; ++mi)
      #pragma unroll
      for (int ni = 0; ni < 2; ++ni) {
        acc[mi + 4][ni] = MF(af[mi][0], bv[ni][0], acc[mi + 4][ni]);
        acc[mi + 4][ni] = MF(af[mi][1], bv[ni][1], acc[mi + 4][ni]);
      }
    __builtin_amdgcn_s_setprio(0);
    asm volatile("s_barrier" ::: "memory");
    // ---- phase 3: MFMA Q3 (mi4-7, ni2-3); vmcnt hidden behind MFMA ----
    if (s < HT) STAGE(s++);
    asm volatile("s_barrier" ::: "memory");
    __builtin_amdgcn_s_setprio(1);
    #pragma unroll
    for (int mi = 0; mi < 4; ++mi)
      #pragma unroll
      for (int ni = 2; ni < 4; ++ni) {
        acc[mi + 4][ni] = MF(af[mi][0], bv[ni][0], acc[mi + 4][ni]);
        acc[mi + 4][ni] = MF(af[mi][1], bv[ni][1], acc[mi + 4][ni]);
      }
    __builtin_amdgcn_s_setprio(0);
    if (kt < NT - 2)       asm volatile("s_waitcnt vmcnt(6)" ::: "memory");
    else if (kt == NT - 2) asm volatile("s_waitcnt vmcnt(0)" ::: "memory");
    asm volatile("s_barrier" ::: "memory");
  }

  // ---- epilogue: LDS repack (f32 col-major, pad 20, row-XOR) -> coalesced stores ----
  // D mapping: col=l&15 (fr), row=(l>>4)*4+i (kq,i) [m89-verified]
  const int col0 = nt * 256 + wc * 64 + fr;
  float bvv[4];
  #pragma unroll
  for (int ni = 0; ni < 4; ++ni) bvv[ni] = bias[(size_t)e * HID + col0 + ni * 16];

  float* lsl = (float*)lds;                 // [2][256][20] f32
  const int rs = tid >> 8;                  // read: slice
  const int rr = (tid >> 4) & 15;           //       row in slice
  const int rc = (tid & 15) * 16;           //       col base (16 cols/thread)
  #pragma unroll
  for (int mi = 0; mi < 8; ++mi) {
    __syncthreads();
    #pragma unroll
    for (int ni = 0; ni < 4; ++ni) {
      const int c = wc * 64 + ni * 16 + fr;
      f32x4 v = acc[mi][ni];
      #pragma unroll
      for (int i = 0; i < 4; ++i) v[i] += bvv[ni];
      const int fi = wr * 5120 + c * 20 + ((kq * 4) ^ ((((c >> 4) & 3)) << 2));
      *(f32x4*)(lsl + fi) = v;
    }
    __syncthreads();
    const int rgl = mt * 256 + rs * 128 + mi * 16 + rr;
    uint16_t* cp = C + ((size_t)e * M + rgl) * HID + nt * 256 + rc;
    u16x8 o0, o1;
    #pragma unroll
    for (int j = 0; j < 8; ++j) {
      const int c0 = rc + j, c1 = rc + 8 + j;
      o0[j] = f2bf(lsl[rs * 5120 + c0 * 20 + (rr ^ ((((c0 >> 4) & 3)) << 2))]);
      o1[j] = f2bf(lsl[rs * 5120 + c1 * 20 + (rr ^ ((((c1 >> 4) & 3)) << 2))]);
    }
    *(u16x8*)cp = o0;
    *(u16x8*)(cp + 8) = o1;
  }
}

// ---------------- LayerNorm + ReLU, in place on bf16 [E*CB][HID] ----------------
__global__ __launch_bounds__(256) void ln_relu(uint16_t* __restrict__ h,
                                               const float* __restrict__ g,
                                               const float* __restrict__ be,
                                               int kshift) {        // e = row >> kshift
  const int wid = threadIdx.x >> 6, l = threadIdx.x & 63;
  const long row = (long)blockIdx.x * 4 + wid;
  const int e = (int)(row >> kshift);
  uint16_t* p = h + row * HID;

  u16x8 s0 = *(const u16x8*)(p + l * 8);
  u16x8 s1 = *(const u16x8*)(p + 512 + l * 8);
  float v[16];
  #pragma unroll
  for (int j = 0; j < 8; ++j) { v[j] = bf2f(s0[j]); v[8 + j] = bf2f(s1[j]); }

  float sum = 0.f, sq = 0.f;
  #pragma unroll
  for (int j = 0; j < 16; ++j) { sum += v[j]; sq += v[j] * v[j]; }
  #pragma unroll
  for (int m = 1; m < 64; m <<= 1) {
    sum += __shfl_xor(sum, m);
    sq  += __shfl_xor(sq, m);
  }
  const float mu  = sum * (1.0f / HID);
  const float var = sq * (1.0f / HID) - mu * mu;
  const float rs  = rsqrtf(var + LN_EPS);

  const float* gp = g  + (size_t)e * HID;
  const float* bp = be + (size_t)e * HID;
  u16x8 o0, o1;
  #pragma unroll
  for (int j = 0; j < 8; ++j) {
    const int c0 = l * 8 + j, c1 = 512 + l * 8 + j;
    float x0 = (v[j]     - mu) * rs * gp[c0] + bp[c0];
    float x1 = (v[8 + j] - mu) * rs * gp[c1] + bp[c1];
    o0[j] = f2bf(fmaxf(x0, 0.f));
    o1[j] = f2bf(fmaxf(x1, 0.f));
  }
  *(u16x8*)(p + l * 8) = o0;
  *(u16x8*)(p + 512 + l * 8) = o1;
}

// ------- fused LN2 + ReLU + head dot + min: reads pre-LN h2, writes q/qs only -------
__global__ __launch_bounds__(256) void ln_head(const uint16_t* __restrict__ h,
                                               const float* __restrict__ g,
                                               const float* __restrict__ be,
                                               const float* __restrict__ W3,
                                               const float* __restrict__ b3,
                                               float* __restrict__ out,
                                               int b0, int CB) {
  __shared__ float qsh[EN];
  const int wv = threadIdx.x >> 6, l = threadIdx.x & 63;
  const long b = blockIdx.x;
  #pragma unroll
  for (int ee = 0; ee < 2; ++ee) {
    const int e = wv + ee * 4;
    const uint16_t* p = h + ((size_t)e * CB + b) * HID;
    u16x8 s0 = *(const u16x8*)(p + l * 8);
    u16x8 s1 = *(const u16x8*)(p + 512 + l * 8);
    float v[16];
    #pragma unroll
    for (int j = 0; j < 8; ++j) { v[j] = bf2f(s0[j]); v[8 + j] = bf2f(s1[j]); }
    float sum = 0.f, sq = 0.f;
    #pragma unroll
    for (int j = 0; j < 16; ++j) { sum += v[j]; sq += v[j] * v[j]; }
    #pragma unroll
    for (int m = 1; m < 64; m <<= 1) {
      sum += __shfl_xor(sum, m);
      sq  += __shfl_xor(sq, m);
    }
    const float mu  = sum * (1.0f / HID);
    const float var = sq * (1.0f / HID) - mu * mu;
    const float rs  = rsqrtf(var + LN_EPS);
    const float* gp = g  + (size_t)e * HID;
    const float* bp = be + (size_t)e * HID;
    const float* w  = W3 + (size_t)e * HID;
    float dot = 0.f;
    #pragma unroll
    for (int j = 0; j < 8; ++j) {
      const int c0 = l * 8 + j, c1 = 512 + l * 8 + j;
      float x0 = fmaxf((v[j]     - mu) * rs * gp[c0] + bp[c0], 0.f);
      float x1 = fmaxf((v[8 + j] - mu) * rs * gp[c1] + bp[c1], 0.f);
      dot += x0 * w[c0] + x1 * w[c1];
    }
    #pragma unroll
    for (int m = 1; m < 64; m <<= 1) dot += __shfl_xor(dot, m);
    if (l == 0) {
      const float qe = dot + b3[e];
      qsh[e] = qe;
      out[BATCH + (size_t)e * BATCH + b0 + b] = qe;   // qs
    }
  }
  __syncthreads();
  if (threadIdx.x == 0) {
    float m = qsh[0];
    #pragma unroll
    for (int i = 1; i < EN; ++i) m = fminf(m, qsh[i]);
    out[b0 + b] = m;                                   // q
  }
}

extern "C" void kernel_launch(void* const* d_in, const int* in_sizes, int n_in,
                              void* d_out, int out_size, void* d_ws, size_t ws_size,
                              hipStream_t stream) {
  const float* x   = (const float*)d_in[0];
  const float* W1  = (const float*)d_in[1];
  const float* b1  = (const float*)d_in[2];
  const float* g1  = (const float*)d_in[3];
  const float* be1 = (const float*)d_in[4];
  const float* W2  = (const float*)d_in[5];
  const float* b2  = (const float*)d_in[6];
  const float* g2  = (const float*)d_in[7];
  const float* be2 = (const float*)d_in[8];
  const float* W3  = (const float*)d_in[9];
  const float* b3  = (const float*)d_in[10];
  float* out = (float*)d_out;

  // ---- fixed workspace region: converted inputs (40 MB) ----
  char* ws = (char*)d_ws;
  uint16_t* xb  = (uint16_t*)ws; ws += (size_t)BATCH * DIN * 2;      // 16 MB
  uint16_t* w1t = (uint16_t*)ws; ws += (size_t)EN * DIN * HID * 2;   // 8 MB
  uint16_t* w2t = (uint16_t*)ws; ws += (size_t)EN * HID * HID * 2;   // 16 MB
  size_t fixed = (size_t)(ws - (char*)d_ws);

  // ---- batch-chunk size CB (power of 2, >=256) so h1+h2 fit in workspace ----
  size_t avail = (ws_size > fixed) ? (ws_size - fixed) : 0;
  const size_t per_row = 2ULL * EN * HID * 2ULL;   // h1+h2 bytes per batch row
  int CB = BATCH;
  while (CB > 256 && (size_t)CB * per_row > avail) CB >>= 1;
  const int nchunks = BATCH / CB;
  const int kshift = __builtin_ctz(CB);

  uint16_t* h1 = (uint16_t*)ws; ws += (size_t)EN * CB * HID * 2;
  uint16_t* h2 = (uint16_t*)ws;

  // ---- one-time conversions ----
  cvt_bf16<<<(BATCH * DIN / 4 + 255) / 256, 256, 0, stream>>>(x, xb, (long)BATCH * DIN);
  transpose_cvt<<<dim3(HID / 32, DIN / 32, EN), 256, 0, stream>>>(W1, w1t, DIN, HID);
  transpose_cvt<<<dim3(HID / 32, HID / 32, EN), 256, 0, stream>>>(W2, w2t, HID, HID);

  const int gblocks = (CB / 256) * (HID / 256) * EN;

  for (int c = 0; c < nchunks; ++c) {
    const int b0 = c * CB;
    gemm256<<<gblocks, 512, 0, stream>>>(xb + (size_t)b0 * DIN, (size_t)0,
                                         w1t, b1, h1, CB, DIN);
    ln_relu<<<(EN * CB) / 4, 256, 0, stream>>>(h1, g1, be1, kshift);
    gemm256<<<gblocks, 512, 0, stream>>>(h1, (size_t)CB * HID,
                                         w2t, b2, h2, CB, HID);
    ln_head<<<CB, 256, 0, stream>>>(h2, g2, be2, W3, b3, out, b0, CB);
  }
}

// Round 5
// 677.465 us; speedup vs baseline: 1.0483x; 1.0483x over previous
//
#include <hip/hip_runtime.h>
#include <hip/hip_bf16.h>
#include <stdint.h>

#define EN    8
#define DIN   512
#define HID   1024
#define BATCH 16384
#define LN_EPS 1e-5f

#define BM 256
#define BN 128
#define BK 32
// per ring buffer: A 256*32*2=16384 B, B 128*32*2=8192 B -> 24576; x3 ring = 73728 B LDS

typedef __bf16   bf16x8 __attribute__((ext_vector_type(8)));
typedef float    f32x4  __attribute__((ext_vector_type(4)));
typedef uint16_t u16x8  __attribute__((ext_vector_type(8)));
typedef uint16_t u16x4  __attribute__((ext_vector_type(4)));
typedef float    fl4    __attribute__((ext_vector_type(4)));

__device__ __forceinline__ uint16_t f2bf(float f) {
  uint32_t x = __builtin_bit_cast(uint32_t, f);
  uint32_t r = (x + 0x7fffu + ((x >> 16) & 1u)) >> 16;  // RNE
  return (uint16_t)r;
}
__device__ __forceinline__ float bf2f(uint16_t u) {
  return __builtin_bit_cast(float, (uint32_t)u << 16);
}

__device__ __forceinline__ void gload16(const uint16_t* g, uint16_t* lds) {
  __builtin_amdgcn_global_load_lds(
      (const __attribute__((address_space(1))) uint32_t*)g,
      (__attribute__((address_space(3))) uint32_t*)lds, 16, 0, 0);
}

__device__ __forceinline__ f32x4 MF(bf16x8 a, bf16x8 b, f32x4 c) {
  return __builtin_amdgcn_mfma_f32_16x16x32_bf16(a, b, c, 0, 0, 0);
}

// ---------------- conversion: fp32 -> bf16 ----------------
__global__ __launch_bounds__(256) void cvt_bf16(const float* __restrict__ src,
                                                uint16_t* __restrict__ dst, long n) {
  long i = ((long)blockIdx.x * 256 + threadIdx.x) * 4;
  if (i >= n) return;
  fl4 v = *(const fl4*)(src + i);
  u16x4 o;
  #pragma unroll
  for (int j = 0; j < 4; ++j) o[j] = f2bf(v[j]);
  *(u16x4*)(dst + i) = o;
}

// ---------------- transpose + convert: [E][R][C] fp32 -> [E][C][R] bf16 ----------------
__global__ __launch_bounds__(256) void transpose_cvt(const float* __restrict__ src,
                                                     uint16_t* __restrict__ dst,
                                                     int R, int C) {
  __shared__ float tile[32][33];
  const int e = blockIdx.z;
  const int c0 = blockIdx.x * 32;
  const int r0 = blockIdx.y * 32;
  const int tx = threadIdx.x & 31, ty = threadIdx.x >> 5;
  const float* s = src + (size_t)e * R * C;
  uint16_t*    d = dst + (size_t)e * R * C;
  #pragma unroll
  for (int i = 0; i < 32; i += 8)
    tile[ty + i][tx] = s[(size_t)(r0 + ty + i) * C + (c0 + tx)];
  __syncthreads();
  #pragma unroll
  for (int i = 0; i < 32; i += 8)
    d[(size_t)(c0 + ty + i) * R + (r0 + tx)] = f2bf(tile[tx][ty + i]);
}

// ============ 256x128 GEMM, BK=32, 3-buffer LDS ring, 2 blocks/CU ============
// C[e][M][HID] = A[e][M][K] * Bt[e][HID][K]^T + bias[e][HID]
// 512 threads = 8 waves (4M x 2N), wave tile 64x64, acc 64 VGPR.
// One barrier + one counted vmcnt per K-tile; waves/blocks drift -> TLP overlap.
// Swizzle: 16B unit u at row r holds logical unit u ^ swz(r), swz(r)=(r^(r>>2))&3.
__global__ __launch_bounds__(512, 4) void gemm_rb(
    const uint16_t* __restrict__ A, size_t a_estride,
    const uint16_t* __restrict__ Bt,      // [E][HID][K]
    const float*    __restrict__ bias,    // [E][HID]
    uint16_t*       __restrict__ C,       // [E][M][HID]
    int M, int K) {
  __shared__ __attribute__((aligned(16))) char lds[73728];
  const int tid = threadIdx.x;
  const int bx  = blockIdx.x;
  const int e   = bx & 7;                 // XCD pinning: member e -> XCD e
  const int t   = bx >> 3;
  const int mt  = t >> 3;                 // nt inner: consecutive blocks share A panel
  const int nt  = t & 7;                  // HID/BN = 8
  const int NT  = K >> 5;                 // K-tiles of 32

  const uint16_t* Ae = A + (size_t)e * a_estride + (size_t)(mt * BM) * K;
  const uint16_t* Be = Bt + ((size_t)e * HID + nt * BN) * K;

  const int l  = tid & 63, wid = tid >> 6;
  const int wr = wid >> 1, wc = wid & 1;  // 4 x 2 waves
  const int fr = l & 15, kq = l >> 4;
  const int swf = (fr ^ (fr >> 2)) & 3;   // swz(row) depends only on row&3 == fr&3... (see below)

  // staging: thread t -> row t>>2 (0..127), phys unit t&3; source logical unit pre-swizzled
  const int srow  = tid >> 2;
  const int sunit = (tid & 3) ^ ((srow ^ (srow >> 2)) & 3);
  const uint16_t* pA = Ae + (size_t)srow * K + sunit * 8;   // +g*128*K +kt*32
  const uint16_t* pB = Be + (size_t)srow * K + sunit * 8;   // +kt*32
  char* const ld_t = lds + tid * 16;

  // frag read byte offsets within a ring buffer.
  // A row = wr*64 + mi*16 + fr  (low 4 bits = fr -> swz uses fr bits only: (row^(row>>2))&3
  //   = (fr ^ (fr>>2)) & 3 when (row>>2)&3 has no contribution from mi*16/wr*64 bits 2-3...
  //   mi*16: bit4+, wr*64: bit6+ -> row>>2 bits 0-1 come from fr>>2 only. OK.)
  const int aoff = (wr * 64 + fr) * 64 + ((kq ^ swf) << 4);           // + mi*1024
  const int boff = 16384 + (wc * 64 + fr) * 64 + ((kq ^ swf) << 4);   // + ni*1024

  f32x4 acc[4][4];
  #pragma unroll
  for (int i = 0; i < 4; ++i)
    #pragma unroll
    for (int j = 0; j < 4; ++j) acc[i][j] = (f32x4)0.0f;

  auto STAGE = [&](int kt) {
    char* db = ld_t + (kt % 3) * 24576;
    const uint16_t* a0 = pA + kt * BK;
    gload16(a0, (uint16_t*)db);                                // A rows 0..127
    gload16(a0 + (size_t)128 * K, (uint16_t*)(db + 8192));     // A rows 128..255
    gload16(pB + kt * BK, (uint16_t*)(db + 16384));            // B rows 0..127
  };

  STAGE(0);
  STAGE(1);
  asm volatile("s_waitcnt vmcnt(3)" ::: "memory");  // tile 0 landed
  __builtin_amdgcn_s_barrier();

  for (int kt = 0; kt < NT; ++kt) {
    if (kt + 2 < NT) STAGE(kt + 2);                 // ring slot (kt+2)%3: free since barrier kt-1
    const char* rb = lds + (kt % 3) * 24576;
    bf16x8 af[4], bv[4];
    #pragma unroll
    for (int mi = 0; mi < 4; ++mi) af[mi] = *(const bf16x8*)(rb + aoff + mi * 1024);
    #pragma unroll
    for (int ni = 0; ni < 4; ++ni) bv[ni] = *(const bf16x8*)(rb + boff + ni * 1024);
    __builtin_amdgcn_s_setprio(1);
    #pragma unroll
    for (int ni = 0; ni < 4; ++ni)
      #pragma unroll
      for (int mi = 0; mi < 4; ++mi)
        acc[mi][ni] = MF(af[mi], bv[ni], acc[mi][ni]);
    __builtin_amdgcn_s_setprio(0);
    if (kt + 2 < NT)      asm volatile("s_waitcnt vmcnt(3)" ::: "memory");  // kt+1 landed
    else if (kt + 1 < NT) asm volatile("s_waitcnt vmcnt(0)" ::: "memory");
    if (kt + 1 < NT) __builtin_amdgcn_s_barrier();
  }

  // epilogue: bias + direct bf16 stores. D mapping: col=l&15, row=(l>>4)*4+i [m89]
  const int col0 = nt * BN + wc * 64 + fr;
  const int row0 = mt * BM + wr * 64 + kq * 4;
  float bvv[4];
  #pragma unroll
  for (int ni = 0; ni < 4; ++ni) bvv[ni] = bias[(size_t)e * HID + col0 + ni * 16];
  #pragma unroll
  for (int mi = 0; mi < 4; ++mi) {
    #pragma unroll
    for (int i = 0; i < 4; ++i) {
      const int rg = row0 + mi * 16 + i;
      uint16_t* cp = C + ((size_t)e * M + rg) * HID + col0;
      #pragma unroll
      for (int ni = 0; ni < 4; ++ni)
        cp[ni * 16] = f2bf(acc[mi][ni][i] + bvv[ni]);
    }
  }
}

// ---------------- LayerNorm + ReLU, in place on bf16 [E*CB][HID] ----------------
__global__ __launch_bounds__(256) void ln_relu(uint16_t* __restrict__ h,
                                               const float* __restrict__ g,
                                               const float* __restrict__ be,
                                               int kshift) {        // e = row >> kshift
  const int wid = threadIdx.x >> 6, l = threadIdx.x & 63;
  const long row = (long)blockIdx.x * 4 + wid;
  const int e = (int)(row >> kshift);
  uint16_t* p = h + row * HID;

  u16x8 s0 = *(const u16x8*)(p + l * 8);
  u16x8 s1 = *(const u16x8*)(p + 512 + l * 8);
  float v[16];
  #pragma unroll
  for (int j = 0; j < 8; ++j) { v[j] = bf2f(s0[j]); v[8 + j] = bf2f(s1[j]); }

  float sum = 0.f, sq = 0.f;
  #pragma unroll
  for (int j = 0; j < 16; ++j) { sum += v[j]; sq += v[j] * v[j]; }
  #pragma unroll
  for (int m = 1; m < 64; m <<= 1) {
    sum += __shfl_xor(sum, m);
    sq  += __shfl_xor(sq, m);
  }
  const float mu  = sum * (1.0f / HID);
  const float var = sq * (1.0f / HID) - mu * mu;
  const float rs  = rsqrtf(var + LN_EPS);

  const float* gp = g  + (size_t)e * HID;
  const float* bp = be + (size_t)e * HID;
  u16x8 o0, o1;
  #pragma unroll
  for (int j = 0; j < 8; ++j) {
    const int c0 = l * 8 + j, c1 = 512 + l * 8 + j;
    float x0 = (v[j]     - mu) * rs * gp[c0] + bp[c0];
    float x1 = (v[8 + j] - mu) * rs * gp[c1] + bp[c1];
    o0[j] = f2bf(fmaxf(x0, 0.f));
    o1[j] = f2bf(fmaxf(x1, 0.f));
  }
  *(u16x8*)(p + l * 8) = o0;
  *(u16x8*)(p + 512 + l * 8) = o1;
}

// ------- fused LN2 + ReLU + head dot + min: reads pre-LN h2, writes q/qs only -------
__global__ __launch_bounds__(256) void ln_head(const uint16_t* __restrict__ h,
                                               const float* __restrict__ g,
                                               const float* __restrict__ be,
                                               const float* __restrict__ W3,
                                               const float* __restrict__ b3,
                                               float* __restrict__ out,
                                               int b0, int CB) {
  __shared__ float qsh[EN];
  const int wv = threadIdx.x >> 6, l = threadIdx.x & 63;
  const long b = blockIdx.x;
  #pragma unroll
  for (int ee = 0; ee < 2; ++ee) {
    const int e = wv + ee * 4;
    const uint16_t* p = h + ((size_t)e * CB + b) * HID;
    u16x8 s0 = *(const u16x8*)(p + l * 8);
    u16x8 s1 = *(const u16x8*)(p + 512 + l * 8);
    float v[16];
    #pragma unroll
    for (int j = 0; j < 8; ++j) { v[j] = bf2f(s0[j]); v[8 + j] = bf2f(s1[j]); }
    float sum = 0.f, sq = 0.f;
    #pragma unroll
    for (int j = 0; j < 16; ++j) { sum += v[j]; sq += v[j] * v[j]; }
    #pragma unroll
    for (int m = 1; m < 64; m <<= 1) {
      sum += __shfl_xor(sum, m);
      sq  += __shfl_xor(sq, m);
    }
    const float mu  = sum * (1.0f / HID);
    const float var = sq * (1.0f / HID) - mu * mu;
    const float rs  = rsqrtf(var + LN_EPS);
    const float* gp = g  + (size_t)e * HID;
    const float* bp = be + (size_t)e * HID;
    const float* w  = W3 + (size_t)e * HID;
    float dot = 0.f;
    #pragma unroll
    for (int j = 0; j < 8; ++j) {
      const int c0 = l * 8 + j, c1 = 512 + l * 8 + j;
      float x0 = fmaxf((v[j]     - mu) * rs * gp[c0] + bp[c0], 0.f);
      float x1 = fmaxf((v[8 + j] - mu) * rs * gp[c1] + bp[c1], 0.f);
      dot += x0 * w[c0] + x1 * w[c1];
    }
    #pragma unroll
    for (int m = 1; m < 64; m <<= 1) dot += __shfl_xor(dot, m);
    if (l == 0) {
      const float qe = dot + b3[e];
      qsh[e] = qe;
      out[BATCH + (size_t)e * BATCH + b0 + b] = qe;   // qs
    }
  }
  __syncthreads();
  if (threadIdx.x == 0) {
    float m = qsh[0];
    #pragma unroll
    for (int i = 1; i < EN; ++i) m = fminf(m, qsh[i]);
    out[b0 + b] = m;                                   // q
  }
}

extern "C" void kernel_launch(void* const* d_in, const int* in_sizes, int n_in,
                              void* d_out, int out_size, void* d_ws, size_t ws_size,
                              hipStream_t stream) {
  const float* x   = (const float*)d_in[0];
  const float* W1  = (const float*)d_in[1];
  const float* b1  = (const float*)d_in[2];
  const float* g1  = (const float*)d_in[3];
  const float* be1 = (const float*)d_in[4];
  const float* W2  = (const float*)d_in[5];
  const float* b2  = (const float*)d_in[6];
  const float* g2  = (const float*)d_in[7];
  const float* be2 = (const float*)d_in[8];
  const float* W3  = (const float*)d_in[9];
  const float* b3  = (const float*)d_in[10];
  float* out = (float*)d_out;

  // ---- fixed workspace region: converted inputs (40 MB) ----
  char* ws = (char*)d_ws;
  uint16_t* xb  = (uint16_t*)ws; ws += (size_t)BATCH * DIN * 2;      // 16 MB
  uint16_t* w1t = (uint16_t*)ws; ws += (size_t)EN * DIN * HID * 2;   // 8 MB
  uint16_t* w2t = (uint16_t*)ws; ws += (size_t)EN * HID * HID * 2;   // 16 MB
  size_t fixed = (size_t)(ws - (char*)d_ws);

  // ---- batch-chunk size CB (power of 2, >=256) so h1+h2 fit in workspace ----
  size_t avail = (ws_size > fixed) ? (ws_size - fixed) : 0;
  const size_t per_row = 2ULL * EN * HID * 2ULL;   // h1+h2 bytes per batch row
  int CB = BATCH;
  while (CB > 256 && (size_t)CB * per_row > avail) CB >>= 1;
  const int nchunks = BATCH / CB;
  const int kshift = __builtin_ctz(CB);

  uint16_t* h1 = (uint16_t*)ws; ws += (size_t)EN * CB * HID * 2;
  uint16_t* h2 = (uint16_t*)ws;

  // ---- one-time conversions ----
  cvt_bf16<<<(BATCH * DIN / 4 + 255) / 256, 256, 0, stream>>>(x, xb, (long)BATCH * DIN);
  transpose_cvt<<<dim3(HID / 32, DIN / 32, EN), 256, 0, stream>>>(W1, w1t, DIN, HID);
  transpose_cvt<<<dim3(HID / 32, HID / 32, EN), 256, 0, stream>>>(W2, w2t, HID, HID);

  const int gblocks = (CB / BM) * (HID / BN) * EN;

  for (int c = 0; c < nchunks; ++c) {
    const int b0 = c * CB;
    gemm_rb<<<gblocks, 512, 0, stream>>>(xb + (size_t)b0 * DIN, (size_t)0,
                                         w1t, b1, h1, CB, DIN);
    ln_relu<<<(EN * CB) / 4, 256, 0, stream>>>(h1, g1, be1, kshift);
    gemm_rb<<<gblocks, 512, 0, stream>>>(h1, (size_t)CB * HID,
                                         w2t, b2, h2, CB, HID);
    ln_head<<<CB, 256, 0, stream>>>(h2, g2, be2, W3, b3, out, b0, CB);
  }
}